// Round 1
// baseline (1590.380 us; speedup 1.0000x reference)
//
#include <hip/hip_runtime.h>
#include <math.h>

#define N 1024
#define C 81
#define F 1024
#define K 100
#define NC1 80              // C-1 foreground classes
#define SELCAP 4096         // LDS select capacity (u64 keys, 32 KiB)

#define SCORE_THRESH 0.05f
#define NMS_THRESH   0.5f
#define BBOX_CLIP    4.135166556742356f   // log(1000/16)
#define IMG_W1       1215.0f
#define IMG_H1       799.0f

typedef unsigned long long u64;
typedef unsigned int u32;

// ---- per-row softmax score for class cl, BIT-EXACT replica of the old wave
// butterfly: leaf[j] = e(L[j]) (+ e(L[64+j]) for j<17), then xor-tree sum.
// fmax is order-exact; the add tree below reproduces lane0's butterfly value.
__device__ float score_row(const float* __restrict__ logits, int n, int cl)
{
    const float* Lr = logits + n * C;
    float m = -INFINITY;
    for (int i = 0; i < C; ++i) m = fmaxf(m, Lr[i]);
    float acc[32];
    #pragma unroll
    for (int j = 0; j < 32; ++j) {
        float lo = expf(Lr[j] - m);
        if (j < C - 64) lo = lo + expf(Lr[64 + j] - m);   // j<17
        float hi = expf(Lr[j + 32] - m);                  // lanes 32..63: e2==0
        acc[j] = lo + hi;                                 // butterfly level off=32
    }
    #pragma unroll
    for (int off = 16; off; off >>= 1) {
        #pragma unroll
        for (int j = 0; j < off; ++j) acc[j] = acc[j] + acc[j + off];
    }
    return expf(Lr[cl] - m) / acc[0];
}

// ---- decode one (proposal idx, class cl) box — expressions verbatim from the
// previous (absmax==0) kernel so contraction/codegen matches.
__device__ float4 decode_box(const float* __restrict__ pboxes,
                             const float* __restrict__ boxreg, int idx, int cl)
{
    float4 pb = ((const float4*)pboxes)[idx];
    float4 r  = *(const float4*)(boxreg + (size_t)idx * (C * 4) + cl * 4);
    float w  = pb.z - pb.x + 1.0f, h = pb.w - pb.y + 1.0f;
    float cx = pb.x + 0.5f * w,  cy = pb.y + 0.5f * h;
    float dx = r.x / 10.0f, dy = r.y / 10.0f;
    float dw = fminf(r.z / 5.0f, BBOX_CLIP);
    float dh = fminf(r.w / 5.0f, BBOX_CLIP);
    float pcx = dx * w + cx, pcy = dy * h + cy;
    float pw = expf(dw) * w, ph = expf(dh) * h;
    float x1 = pcx - 0.5f * pw,        y1 = pcy - 0.5f * ph;
    float x2 = pcx + 0.5f * pw - 1.0f, y2 = pcy + 0.5f * ph - 1.0f;
    x1 = fminf(fmaxf(x1, 0.0f), IMG_W1);
    y1 = fminf(fmaxf(y1, 0.0f), IMG_H1);
    x2 = fminf(fmaxf(x2, 0.0f), IMG_W1);
    y2 = fminf(fmaxf(y2, 0.0f), IMG_H1);
    return make_float4(x1, y1, x2, y2);
}

// ---------------- fused per-class: softmax -> threshold -> sort -> NMS ------
// one block per foreground class. Redundant row-stats across blocks (~81 exp
// per row per block) replace the probsT/decT transpose round-trip and a kernel
// boundary. Only post-threshold candidates get decoded.
// Outputs per class c: ckey[c*N + 0..kc) compact keys (score<<32 | ~(c*N+rank));
// cbox/corig indexed by RANK (c*N + rank) for the gather; kc_g[c] = kept count.
__global__ __launch_bounds__(256) void k_class(
    const float* __restrict__ logits, const float* __restrict__ boxreg,
    const float* __restrict__ pboxes, u64* __restrict__ ckey,
    float4* __restrict__ cbox, int* __restrict__ corig, int* __restrict__ kc_g)
{
    int c = blockIdx.x;            // foreground class (label = c+1)
    int t = threadIdx.x;
    __shared__ u64    skey64[N];
    __shared__ int    scnt[256];
    __shared__ float4 sbox[N];
    __shared__ float  sarea[N];
    __shared__ int    skeep[N];

    if (t == 0) kc_g[c] = 0;

    // scores for rows t, t+256, t+512, t+768
    float s0 = score_row(logits, t,       c + 1);
    float s1 = score_row(logits, t + 256, c + 1);
    float s2 = score_row(logits, t + 512, c + 1);
    float s3 = score_row(logits, t + 768, c + 1);
    int f0 = s0 > SCORE_THRESH, f1 = s1 > SCORE_THRESH;
    int f2 = s2 > SCORE_THRESH, f3 = s3 > SCORE_THRESH;
    int mycount = f0 + f1 + f2 + f3;
    scnt[t] = mycount;
    __syncthreads();
    for (int off = 1; off < 256; off <<= 1) {
        int v = scnt[t];
        int a = (t >= off) ? scnt[t - off] : 0;
        __syncthreads();
        scnt[t] = v + a;
        __syncthreads();
    }
    int base = scnt[t] - mycount;
    int V = scnt[255];
    {
        int pos = base;
        if (f0) skey64[pos++] = ((u64)__float_as_uint(s0) << 32) | (u32)~(u32)(t);
        if (f1) skey64[pos++] = ((u64)__float_as_uint(s1) << 32) | (u32)~(u32)(t + 256);
        if (f2) skey64[pos++] = ((u64)__float_as_uint(s2) << 32) | (u32)~(u32)(t + 512);
        if (f3) skey64[pos++] = ((u64)__float_as_uint(s3) << 32) | (u32)~(u32)(t + 768);
    }
    __syncthreads();
    if (V == 0) return;

    if (V <= 64) {
        if (t < 64) {
            int lane = t;
            u64 key = (lane < V) ? skey64[lane] : 0ull;
            // descending bitonic over 64 lanes (keys unique; 0-pad sinks)
            for (int k = 2; k <= 64; k <<= 1) {
                for (int j = k >> 1; j > 0; j >>= 1) {
                    u64 other = __shfl_xor(key, j);
                    bool takeMax = (((lane & j) == 0) == ((lane & k) == 0));
                    bool gt = key > other;
                    key = (takeMax == gt) ? key : other;
                }
            }
            bool act = key != 0ull;
            float4 b = make_float4(0.f, 0.f, 0.f, 0.f);
            float area = 0.0f;
            if (act) {
                int idx = (int)(~(u32)(key & 0xffffffffu));
                b = decode_box(pboxes, boxreg, idx, c + 1);
                area = (b.z - b.x + 1.0f) * (b.w - b.y + 1.0f);
                cbox[c * N + lane]  = b;
                corig[c * N + lane] = idx;
            }
            int kept = act ? 1 : 0;
            for (int i = 0; i + 1 < V; ++i) {
                int   ki  = __shfl(kept, i);
                float bix = __shfl(b.x, i), biy = __shfl(b.y, i);
                float biz = __shfl(b.z, i), biw = __shfl(b.w, i);
                float ai  = __shfl(area, i);
                if (ki && lane > i && kept) {
                    float lx = fmaxf(bix, b.x), ly = fmaxf(biy, b.y);
                    float rx = fminf(biz, b.z), ry = fminf(biw, b.w);
                    float ww = fmaxf(rx - lx + 1.0f, 0.0f);
                    float hh = fmaxf(ry - ly + 1.0f, 0.0f);
                    float inter = ww * hh;
                    float iou = inter / (ai + area - inter);
                    if (iou > NMS_THRESH) kept = 0;
                }
            }
            u64 mask = __ballot(kept != 0);
            if (kept) {
                int opos = __popcll(mask & ((1ull << lane) - 1));
                u32 sb = (u32)(key >> 32);
                ckey[c * N + opos] = ((u64)sb << 32) | (u64)(u32)~(u32)(c * N + lane);
            }
            if (lane == 0) kc_g[c] = __popcll(mask);
        }
        return;
    }

    // ---------- fallback: V > 64, LDS bitonic on P = next pow2 ----------
    int P = 128;
    while (P < V) P <<= 1;
    for (int i = V + t; i < P; i += 256) skey64[i] = 0ull;
    __syncthreads();
    for (int k = 2; k <= P; k <<= 1) {
        for (int j = k >> 1; j > 0; j >>= 1) {
            for (int i = t; i < P; i += 256) {
                int ixj = i ^ j;
                if (ixj > i) {
                    u64 a = skey64[i], bb = skey64[ixj];
                    bool desc = ((i & k) == 0);
                    if (desc ? (a < bb) : (a > bb)) { skey64[i] = bb; skey64[ixj] = a; }
                }
            }
            __syncthreads();
        }
    }
    for (int p = t; p < V; p += 256) {
        int idx = (int)(~(u32)(skey64[p] & 0xffffffffu));
        float4 b = decode_box(pboxes, boxreg, idx, c + 1);
        sbox[p]  = b;
        sarea[p] = (b.z - b.x + 1.0f) * (b.w - b.y + 1.0f);
        skeep[p] = 1;
        cbox[c * N + p]  = b;
        corig[c * N + p] = idx;
    }
    __syncthreads();
    for (int i = 0; i < V; ++i) {
        if (skeep[i]) {
            float4 bi = sbox[i];
            float  ai = sarea[i];
            for (int j = i + 1 + t; j < V; j += 256) {
                if (skeep[j]) {
                    float4 bj = sbox[j];
                    float lx = fmaxf(bi.x, bj.x), ly = fmaxf(bi.y, bj.y);
                    float rx = fminf(bi.z, bj.z), ry = fminf(bi.w, bj.w);
                    float ww = fmaxf(rx - lx + 1.0f, 0.0f);
                    float hh = fmaxf(ry - ly + 1.0f, 0.0f);
                    float inter = ww * hh;
                    float iou = inter / (ai + sarea[j] - inter);
                    if (iou > NMS_THRESH) skeep[j] = 0;
                }
            }
        }
        __syncthreads();
    }
    // compact kept keys into ckey[c*N + ...]
    int cnt = 0;
    for (int p = t; p < V; p += 256) cnt += skeep[p];
    scnt[t] = cnt;
    __syncthreads();
    for (int off = 1; off < 256; off <<= 1) {
        int v = scnt[t];
        int a = (t >= off) ? scnt[t - off] : 0;
        __syncthreads();
        scnt[t] = v + a;
        __syncthreads();
    }
    int opos = scnt[t] - cnt;
    for (int p = t; p < V; p += 256) {
        if (skeep[p]) {
            u32 sb = (u32)(skey64[p] >> 32);
            ckey[c * N + opos++] = ((u64)sb << 32) | (u64)(u32)~(u32)(c * N + p);
        }
    }
    if (t == 0) kc_g[c] = scnt[255];
}

// ---------------- exact top-K: gather per-class compacts, bitonic sort ------
__global__ __launch_bounds__(1024) void k_select(
    const int* __restrict__ kc_g, u64* ckey,
    float* __restrict__ sel_score, int* __restrict__ sel_flat)
{
    int t = threadIdx.x;
    __shared__ u64 keys[SELCAP];
    __shared__ int skc[NC1];
    __shared__ int pref[NC1];
    __shared__ int sM;
    __shared__ u64 wk[16];
    __shared__ int wp[16];

    if (t < NC1) skc[t] = kc_g[t];
    __syncthreads();
    if (t == 0) {
        int run = 0;
        for (int c2 = 0; c2 < NC1; ++c2) { pref[c2] = run; run += skc[c2]; }
        sM = run;
    }
    __syncthreads();
    int M = sM;

    if (M <= SELCAP) {
        for (int c2 = 0; c2 < NC1; ++c2) {
            int nn = skc[c2], bb = pref[c2];
            for (int j = t; j < nn; j += 1024) keys[bb + j] = ckey[(size_t)c2 * N + j];
        }
        int P = 128;
        while (P < M) P <<= 1;
        for (int i = M + t; i < P; i += 1024) keys[i] = 0ull;
        __syncthreads();
        for (int k = 2; k <= P; k <<= 1) {
            for (int j = k >> 1; j > 0; j >>= 1) {
                for (int i = t; i < P; i += 1024) {
                    int ixj = i ^ j;
                    if (ixj > i) {
                        u64 a = keys[i], b = keys[ixj];
                        bool desc = ((i & k) == 0);
                        if (desc ? (a < b) : (a > b)) { keys[i] = b; keys[ixj] = a; }
                    }
                }
                __syncthreads();
            }
        }
        if (t < K) {
            u64 key = keys[t];
            sel_score[t] = __uint_as_float((u32)(key >> 32));
            sel_flat[t]  = (int)(~(u32)(key & 0xffffffffu));
        }
        return;
    }

    // exact fallback (tie flood): K rounds of argmax over per-class regions
    for (int kk = 0; kk < K; ++kk) {
        u64 key = 0ull; int pos = -1;
        for (int p = t; p < NC1 * N; p += 1024) {
            int c2 = p >> 10, j = p & 1023;
            if (j < skc[c2]) {
                u64 q = ckey[p];
                if (q > key) { key = q; pos = p; }
            }
        }
        for (int off = 32; off; off >>= 1) {
            u64 ok2 = __shfl_down(key, off);
            int op  = __shfl_down(pos, off);
            if (ok2 > key) { key = ok2; pos = op; }
        }
        if ((t & 63) == 0) { wk[t >> 6] = key; wp[t >> 6] = pos; }
        __syncthreads();
        if (t == 0) {
            for (int w = 1; w < 16; ++w)
                if (wk[w] > key) { key = wk[w]; pos = wp[w]; }
            if (key != 0ull) {
                sel_score[kk] = __uint_as_float((u32)(key >> 32));
                sel_flat[kk]  = (int)(~(u32)(key & 0xffffffffu));
                ckey[pos] = 0ull;
            } else { sel_score[kk] = 0.0f; sel_flat[kk] = 0; }
        }
        __syncthreads();
    }
}

// ---------------- gather outputs ------------------------------------------
// out layout: boxes[K*4] | scores[K] | feats[K*F] | labels[K]  (all f32)
__global__ __launch_bounds__(256) void k_gather(
    const float* __restrict__ sel_score, const int* __restrict__ sel_flat,
    const int* __restrict__ corig, const float4* __restrict__ cbox,
    const float* __restrict__ feats, float* __restrict__ out)
{
    int k = blockIdx.x, t = threadIdx.x;
    float s = sel_score[k];
    bool ok = s > 0.0f;
    float4 b = make_float4(0.f, 0.f, 0.f, 0.f);
    int label = 0, orig = 0;
    if (ok) {
        int flat = sel_flat[k];        // c*N + rank
        orig  = corig[flat];
        b     = cbox[flat];
        label = (flat >> 10) + 1;      // N = 1024
    }
    if (t == 0) {
        out[k * 4 + 0] = b.x; out[k * 4 + 1] = b.y;
        out[k * 4 + 2] = b.z; out[k * 4 + 3] = b.w;
        out[K * 4 + k] = ok ? s : 0.0f;
        out[K * 4 + K + K * F + k] = (float)label;
    }
    const float4* src = (const float4*)(feats + (size_t)orig * F);
    float4* dst = (float4*)(out + K * 4 + K + (size_t)k * F);
    float4 z = make_float4(0.f, 0.f, 0.f, 0.f);
    if (t < F / 4) dst[t] = ok ? src[t] : z;
}

// ---------------------------------------------------------------------------
extern "C" void kernel_launch(void* const* d_in, const int* in_sizes, int n_in,
                              void* d_out, int out_size, void* d_ws, size_t ws_size,
                              hipStream_t stream)
{
    const float* logits = (const float*)d_in[0];   // [N,C]
    const float* boxreg = (const float*)d_in[1];   // [N,C*4]
    const float* pboxes = (const float*)d_in[2];   // [N,4]
    const float* feats  = (const float*)d_in[3];   // [N,F]
    float* out = (float*)d_out;

    char* ws = (char*)d_ws;
    size_t off = 0;
    auto alloc = [&](size_t bytes) {
        size_t cur = off;
        off = (off + bytes + 255) & ~(size_t)255;
        return cur;
    };
    u64*    ckey      = (u64*)   (ws + alloc(sizeof(u64)    * NC1 * N));
    float4* cbox      = (float4*)(ws + alloc(sizeof(float4) * NC1 * N));
    int*    corig     = (int*)   (ws + alloc(sizeof(int)    * NC1 * N));
    int*    kc        = (int*)   (ws + alloc(sizeof(int)    * NC1));
    float*  sel_score = (float*) (ws + alloc(sizeof(float)  * K));
    int*    sel_flat  = (int*)   (ws + alloc(sizeof(int)    * K));

    hipLaunchKernelGGL(k_class, dim3(NC1), dim3(256), 0, stream,
                       logits, boxreg, pboxes, ckey, cbox, corig, kc);
    hipLaunchKernelGGL(k_select, dim3(1), dim3(1024), 0, stream,
                       kc, ckey, sel_score, sel_flat);
    hipLaunchKernelGGL(k_gather, dim3(K), dim3(256), 0, stream,
                       sel_score, sel_flat, corig, cbox, feats, out);
}

// Round 2
// 298.566 us; speedup vs baseline: 5.3267x; 5.3267x over previous
//
#include <hip/hip_runtime.h>
#include <math.h>

#define N 1024
#define C 81
#define F 1024
#define K 100
#define NC1 80              // C-1 foreground classes
#define MAXC (NC1 * N)      // dense candidate capacity
#define HBASE 0x3D00        // hist bucket base: float bits >>16
#define HSIZE 1024          // covers score in (0.05, 1]: buckets 76..640
#define SELCAP 2048         // LDS select capacity

#define SCORE_THRESH 0.05f
#define NMS_THRESH   0.5f
#define BBOX_CLIP    4.135166556742356f   // log(1000/16)
#define IMG_W1       1215.0f
#define IMG_H1       799.0f

typedef unsigned long long u64;
typedef unsigned int u32;

// ---- decode one (proposal idx, class cl) box — expressions verbatim from the
// absmax==0 kernels so contraction/codegen matches.
__device__ float4 decode_box(const float* __restrict__ pboxes,
                             const float* __restrict__ boxreg, int idx, int cl)
{
    float4 pb = ((const float4*)pboxes)[idx];
    float4 r  = *(const float4*)(boxreg + (size_t)idx * (C * 4) + cl * 4);
    float w  = pb.z - pb.x + 1.0f, h = pb.w - pb.y + 1.0f;
    float cx = pb.x + 0.5f * w,  cy = pb.y + 0.5f * h;
    float dx = r.x / 10.0f, dy = r.y / 10.0f;
    float dw = fminf(r.z / 5.0f, BBOX_CLIP);
    float dh = fminf(r.w / 5.0f, BBOX_CLIP);
    float pcx = dx * w + cx, pcy = dy * h + cy;
    float pw = expf(dw) * w, ph = expf(dh) * h;
    float x1 = pcx - 0.5f * pw,        y1 = pcy - 0.5f * ph;
    float x2 = pcx + 0.5f * pw - 1.0f, y2 = pcy + 0.5f * ph - 1.0f;
    x1 = fminf(fmaxf(x1, 0.0f), IMG_W1);
    y1 = fminf(fmaxf(y1, 0.0f), IMG_H1);
    x2 = fminf(fmaxf(x2, 0.0f), IMG_W1);
    y2 = fminf(fmaxf(y2, 0.0f), IMG_H1);
    return make_float4(x1, y1, x2, y2);
}

// ---------------- init: zero hist + counter (graph-capture-safe) ------------
__global__ __launch_bounds__(1024) void k_init(int* __restrict__ hist,
                                               int* __restrict__ counter)
{
    int t = threadIdx.x;
    hist[t] = 0;
    if (t == 0) *counter = 0;
}

// ---------------- fused per-class: softmax -> threshold -> sort -> NMS ------
// one block per foreground class. Scores computed wave-parallel, bit-exact
// replica of the original butterfly (commutativity => all lanes identical).
// Only post-threshold candidates get decoded. Kept keys emitted into dense
// ckey[] via global atomic counter + score histogram (old proven emission).
// cbox/corig indexed by RANK (c*N + rank) for the gather.
__global__ __launch_bounds__(256) void k_class(
    const float* __restrict__ logits, const float* __restrict__ boxreg,
    const float* __restrict__ pboxes, u64* __restrict__ ckey,
    float4* __restrict__ cbox, int* __restrict__ corig,
    int* __restrict__ hist, int* __restrict__ counter)
{
    int c = blockIdx.x;            // foreground class (label = c+1)
    int t = threadIdx.x;
    int wave = t >> 6, lane64 = t & 63;
    __shared__ float  sscore[N];
    __shared__ u64    skey64[N];
    __shared__ int    scnt[256];
    __shared__ float4 sbox[N];
    __shared__ float  sarea[N];
    __shared__ int    skeep[N];

    // ---- wave-parallel softmax score of class c+1 for all N rows ----
    // Each wave handles rows r = wave, wave+4, ... (256 rows). Per row,
    // the exact original computation: v1/v2 load, fmax butterfly, exp,
    // sum butterfly — bit-identical on every lane (commutativity).
    {
        int cl = c + 1;
        #pragma unroll 4
        for (int r = wave; r < N; r += 4) {
            float v1 = logits[r * C + lane64];
            float v2 = (lane64 < C - 64) ? logits[r * C + 64 + lane64] : -INFINITY;
            float m = fmaxf(v1, v2);
            for (int off = 32; off; off >>= 1) m = fmaxf(m, __shfl_xor(m, off));
            float e1 = expf(v1 - m);
            float e2 = (lane64 < C - 64) ? expf(v2 - m) : 0.0f;
            float s = e1 + e2;
            for (int off = 32; off; off >>= 1) s += __shfl_xor(s, off);
            float ec = (cl < 64) ? __shfl(e1, cl) : __shfl(e2, cl - 64);
            if (lane64 == 0) sscore[r] = ec / s;
        }
    }
    __syncthreads();

    float s0 = sscore[t];
    float s1 = sscore[t + 256];
    float s2 = sscore[t + 512];
    float s3 = sscore[t + 768];
    int f0 = s0 > SCORE_THRESH, f1 = s1 > SCORE_THRESH;
    int f2 = s2 > SCORE_THRESH, f3 = s3 > SCORE_THRESH;
    int mycount = f0 + f1 + f2 + f3;
    scnt[t] = mycount;
    __syncthreads();
    for (int off = 1; off < 256; off <<= 1) {
        int v = scnt[t];
        int a = (t >= off) ? scnt[t - off] : 0;
        __syncthreads();
        scnt[t] = v + a;
        __syncthreads();
    }
    int base = scnt[t] - mycount;
    int V = scnt[255];
    {
        int pos = base;
        if (f0) skey64[pos++] = ((u64)__float_as_uint(s0) << 32) | (u32)~(u32)(t);
        if (f1) skey64[pos++] = ((u64)__float_as_uint(s1) << 32) | (u32)~(u32)(t + 256);
        if (f2) skey64[pos++] = ((u64)__float_as_uint(s2) << 32) | (u32)~(u32)(t + 512);
        if (f3) skey64[pos++] = ((u64)__float_as_uint(s3) << 32) | (u32)~(u32)(t + 768);
    }
    __syncthreads();
    if (V == 0) return;

    if (V <= 64) {
        if (t < 64) {
            int lane = t;
            u64 key = (lane < V) ? skey64[lane] : 0ull;
            // descending bitonic over 64 lanes (keys unique; 0-pad sinks)
            for (int k = 2; k <= 64; k <<= 1) {
                for (int j = k >> 1; j > 0; j >>= 1) {
                    u64 other = __shfl_xor(key, j);
                    bool takeMax = (((lane & j) == 0) == ((lane & k) == 0));
                    bool gt = key > other;
                    key = (takeMax == gt) ? key : other;
                }
            }
            bool act = key != 0ull;
            float4 b = make_float4(0.f, 0.f, 0.f, 0.f);
            float area = 0.0f;
            if (act) {
                int idx = (int)(~(u32)(key & 0xffffffffu));
                b = decode_box(pboxes, boxreg, idx, c + 1);
                area = (b.z - b.x + 1.0f) * (b.w - b.y + 1.0f);
                cbox[c * N + lane]  = b;
                corig[c * N + lane] = idx;
            }
            int kept = act ? 1 : 0;
            for (int i = 0; i + 1 < V; ++i) {
                int   ki  = __shfl(kept, i);
                float bix = __shfl(b.x, i), biy = __shfl(b.y, i);
                float biz = __shfl(b.z, i), biw = __shfl(b.w, i);
                float ai  = __shfl(area, i);
                if (ki && lane > i && kept) {
                    float lx = fmaxf(bix, b.x), ly = fmaxf(biy, b.y);
                    float rx = fminf(biz, b.z), ry = fminf(biw, b.w);
                    float ww = fmaxf(rx - lx + 1.0f, 0.0f);
                    float hh = fmaxf(ry - ly + 1.0f, 0.0f);
                    float inter = ww * hh;
                    float iou = inter / (ai + area - inter);
                    if (iou > NMS_THRESH) kept = 0;
                }
            }
            if (kept) {
                int pos = atomicAdd(counter, 1);
                u32 sb = (u32)(key >> 32);
                ckey[pos] = ((u64)sb << 32) | (u64)(u32)~(u32)(c * N + lane);
                atomicAdd(&hist[(int)(sb >> 16) - HBASE], 1);
            }
        }
        return;
    }

    // ---------- fallback: V > 64, LDS bitonic on P = next pow2 ----------
    int P = 128;
    while (P < V) P <<= 1;
    for (int i = V + t; i < P; i += 256) skey64[i] = 0ull;
    __syncthreads();
    for (int k = 2; k <= P; k <<= 1) {
        for (int j = k >> 1; j > 0; j >>= 1) {
            for (int i = t; i < P; i += 256) {
                int ixj = i ^ j;
                if (ixj > i) {
                    u64 a = skey64[i], bb = skey64[ixj];
                    bool desc = ((i & k) == 0);
                    if (desc ? (a < bb) : (a > bb)) { skey64[i] = bb; skey64[ixj] = a; }
                }
            }
            __syncthreads();
        }
    }
    for (int p = t; p < V; p += 256) {
        int idx = (int)(~(u32)(skey64[p] & 0xffffffffu));
        float4 b = decode_box(pboxes, boxreg, idx, c + 1);
        sbox[p]  = b;
        sarea[p] = (b.z - b.x + 1.0f) * (b.w - b.y + 1.0f);
        skeep[p] = 1;
        cbox[c * N + p]  = b;
        corig[c * N + p] = idx;
    }
    __syncthreads();
    for (int i = 0; i < V; ++i) {
        if (skeep[i]) {
            float4 bi = sbox[i];
            float  ai = sarea[i];
            for (int j = i + 1 + t; j < V; j += 256) {
                if (skeep[j]) {
                    float4 bj = sbox[j];
                    float lx = fmaxf(bi.x, bj.x), ly = fmaxf(bi.y, bj.y);
                    float rx = fminf(bi.z, bj.z), ry = fminf(bi.w, bj.w);
                    float ww = fmaxf(rx - lx + 1.0f, 0.0f);
                    float hh = fmaxf(ry - ly + 1.0f, 0.0f);
                    float inter = ww * hh;
                    float iou = inter / (ai + sarea[j] - inter);
                    if (iou > NMS_THRESH) skeep[j] = 0;
                }
            }
        }
        __syncthreads();
    }
    for (int p = t; p < V; p += 256) {
        if (skeep[p]) {
            int pos = atomicAdd(counter, 1);
            u32 sb = (u32)(skey64[p] >> 32);
            ckey[pos] = ((u64)sb << 32) | (u64)(u32)~(u32)(c * N + p);
            atomicAdd(&hist[(int)(sb >> 16) - HBASE], 1);
        }
    }
}

// ---------------- exact top-K via radix-select + small bitonic sort --------
// (verbatim structure from the proven 107 µs version)
__global__ __launch_bounds__(1024) void k_select(
    const int* __restrict__ counter, u64* ckey, const int* __restrict__ hist,
    float* __restrict__ sel_score, int* __restrict__ sel_flat)
{
    int t = threadIdx.x;
    __shared__ u64 keys[SELCAP];
    __shared__ int partial[1024];
    __shared__ int sb_bstar, scount;
    __shared__ u64 wk[16];
    __shared__ int wp[16];

    int M = *counter;
    if (t == 0) { sb_bstar = 0; scount = 0; }

    // phase 1: suffix scan of 1024-bucket histogram -> bucket of K-th key
    int lsum = hist[t];
    partial[t] = lsum;
    __syncthreads();
    for (int off = 1; off < 1024; off <<= 1) {
        int v = partial[t];
        int a = (t + off < 1024) ? partial[t + off] : 0;
        __syncthreads();
        partial[t] = v + a;
        __syncthreads();
    }
    int base = partial[t] - lsum;              // keys in buckets above t
    if (base < K && base + lsum >= K) sb_bstar = t;
    __syncthreads();
    int bstar = sb_bstar;

    // phase 2: compact keys with bucket >= bstar
    for (int p = t; p < M; p += 1024) {
        u64 kk = ckey[p];
        int b = (int)((kk >> 48) & 0xFFFF) - HBASE;
        if (b >= bstar) {
            int pos = atomicAdd(&scount, 1);
            if (pos < SELCAP) keys[pos] = kk;
        }
    }
    __syncthreads();
    int cnt = scount;

    if (cnt > SELCAP) {
        // exact fallback (tie flood): K rounds of argmax over dense ckey
        for (int k = 0; k < K; ++k) {
            u64 key = 0ull; int pos = -1;
            for (int p = t; p < M; p += 1024) {
                u64 kk = ckey[p];
                if (kk > key) { key = kk; pos = p; }
            }
            for (int off = 32; off; off >>= 1) {
                u64 ok2 = __shfl_down(key, off);
                int op = __shfl_down(pos, off);
                if (ok2 > key) { key = ok2; pos = op; }
            }
            if ((t & 63) == 0) { wk[t >> 6] = key; wp[t >> 6] = pos; }
            __syncthreads();
            if (t == 0) {
                for (int w = 1; w < 16; ++w)
                    if (wk[w] > key) { key = wk[w]; pos = wp[w]; }
                if (key != 0ull) {
                    sel_score[k] = __uint_as_float((u32)(key >> 32));
                    sel_flat[k]  = (int)(~(u32)(key & 0xffffffffu));
                    ckey[pos] = 0ull;
                } else { sel_score[k] = 0.0f; sel_flat[k] = 0; }
            }
            __syncthreads();
        }
        return;
    }

    // phase 3: bitonic sort padded selection, emit top K
    int P = 128;
    while (P < cnt) P <<= 1;
    for (int i = cnt + t; i < P; i += 1024) keys[i] = 0ull;
    __syncthreads();
    for (int k = 2; k <= P; k <<= 1) {
        for (int j = k >> 1; j > 0; j >>= 1) {
            for (int i = t; i < P; i += 1024) {
                int ixj = i ^ j;
                if (ixj > i) {
                    u64 a = keys[i], b = keys[ixj];
                    bool desc = ((i & k) == 0);
                    if (desc ? (a < b) : (a > b)) { keys[i] = b; keys[ixj] = a; }
                }
            }
            __syncthreads();
        }
    }
    if (t < K) {
        u64 key = keys[t];
        sel_score[t] = __uint_as_float((u32)(key >> 32));
        sel_flat[t]  = (int)(~(u32)(key & 0xffffffffu));
    }
}

// ---------------- gather outputs ------------------------------------------
// out layout: boxes[K*4] | scores[K] | feats[K*F] | labels[K]  (all f32)
__global__ __launch_bounds__(256) void k_gather(
    const float* __restrict__ sel_score, const int* __restrict__ sel_flat,
    const int* __restrict__ corig, const float4* __restrict__ cbox,
    const float* __restrict__ feats, float* __restrict__ out)
{
    int k = blockIdx.x, t = threadIdx.x;
    float s = sel_score[k];
    bool ok = s > 0.0f;
    float4 b = make_float4(0.f, 0.f, 0.f, 0.f);
    int label = 0, orig = 0;
    if (ok) {
        int flat = sel_flat[k];        // c*N + rank
        orig  = corig[flat];
        b     = cbox[flat];
        label = (flat >> 10) + 1;      // N = 1024
    }
    if (t == 0) {
        out[k * 4 + 0] = b.x; out[k * 4 + 1] = b.y;
        out[k * 4 + 2] = b.z; out[k * 4 + 3] = b.w;
        out[K * 4 + k] = ok ? s : 0.0f;
        out[K * 4 + K + K * F + k] = (float)label;
    }
    const float4* src = (const float4*)(feats + (size_t)orig * F);
    float4* dst = (float4*)(out + K * 4 + K + (size_t)k * F);
    float4 z = make_float4(0.f, 0.f, 0.f, 0.f);
    if (t < F / 4) dst[t] = ok ? src[t] : z;
}

// ---------------------------------------------------------------------------
extern "C" void kernel_launch(void* const* d_in, const int* in_sizes, int n_in,
                              void* d_out, int out_size, void* d_ws, size_t ws_size,
                              hipStream_t stream)
{
    const float* logits = (const float*)d_in[0];   // [N,C]
    const float* boxreg = (const float*)d_in[1];   // [N,C*4]
    const float* pboxes = (const float*)d_in[2];   // [N,4]
    const float* feats  = (const float*)d_in[3];   // [N,F]
    float* out = (float*)d_out;

    char* ws = (char*)d_ws;
    size_t off = 0;
    auto alloc = [&](size_t bytes) {
        size_t cur = off;
        off = (off + bytes + 255) & ~(size_t)255;
        return cur;
    };
    u64*    ckey      = (u64*)   (ws + alloc(sizeof(u64)    * MAXC));
    float4* cbox      = (float4*)(ws + alloc(sizeof(float4) * NC1 * N));
    int*    corig     = (int*)   (ws + alloc(sizeof(int)    * NC1 * N));
    int*    hist      = (int*)   (ws + alloc(sizeof(int)    * HSIZE));
    int*    counter   = (int*)   (ws + alloc(sizeof(int)));
    float*  sel_score = (float*) (ws + alloc(sizeof(float)  * K));
    int*    sel_flat  = (int*)   (ws + alloc(sizeof(int)    * K));

    hipLaunchKernelGGL(k_init, dim3(1), dim3(1024), 0, stream, hist, counter);
    hipLaunchKernelGGL(k_class, dim3(NC1), dim3(256), 0, stream,
                       logits, boxreg, pboxes, ckey, cbox, corig, hist, counter);
    hipLaunchKernelGGL(k_select, dim3(1), dim3(1024), 0, stream,
                       counter, ckey, hist, sel_score, sel_flat);
    hipLaunchKernelGGL(k_gather, dim3(K), dim3(256), 0, stream,
                       sel_score, sel_flat, corig, cbox, feats, out);
}

// Round 3
// 106.104 us; speedup vs baseline: 14.9889x; 2.8139x over previous
//
#include <hip/hip_runtime.h>
#include <math.h>

#define N 1024
#define C 81
#define F 1024
#define K 100
#define NC1 80              // C-1 foreground classes
#define MAXC (NC1 * N)      // dense candidate capacity
#define HBASE 0x3D00        // hist bucket base: float bits >>16
#define HSIZE 1024          // covers score in (0.05, 1]: buckets 76..640
#define SELCAP 2048         // LDS select capacity

#define SCORE_THRESH 0.05f
#define NMS_THRESH   0.5f
#define BBOX_CLIP    4.135166556742356f   // log(1000/16)
#define IMG_W1       1215.0f
#define IMG_H1       799.0f

typedef unsigned long long u64;
typedef unsigned int u32;

// ---- decode one (proposal idx, class cl) box — expressions verbatim from the
// absmax==0 kernels so contraction/codegen matches.
__device__ float4 decode_box(const float* __restrict__ pboxes,
                             const float* __restrict__ boxreg, int idx, int cl)
{
    float4 pb = ((const float4*)pboxes)[idx];
    float4 r  = *(const float4*)(boxreg + (size_t)idx * (C * 4) + cl * 4);
    float w  = pb.z - pb.x + 1.0f, h = pb.w - pb.y + 1.0f;
    float cx = pb.x + 0.5f * w,  cy = pb.y + 0.5f * h;
    float dx = r.x / 10.0f, dy = r.y / 10.0f;
    float dw = fminf(r.z / 5.0f, BBOX_CLIP);
    float dh = fminf(r.w / 5.0f, BBOX_CLIP);
    float pcx = dx * w + cx, pcy = dy * h + cy;
    float pw = expf(dw) * w, ph = expf(dh) * h;
    float x1 = pcx - 0.5f * pw,        y1 = pcy - 0.5f * ph;
    float x2 = pcx + 0.5f * pw - 1.0f, y2 = pcy + 0.5f * ph - 1.0f;
    x1 = fminf(fmaxf(x1, 0.0f), IMG_W1);
    y1 = fminf(fmaxf(y1, 0.0f), IMG_H1);
    x2 = fminf(fmaxf(x2, 0.0f), IMG_W1);
    y2 = fminf(fmaxf(y2, 0.0f), IMG_H1);
    return make_float4(x1, y1, x2, y2);
}

// ---------------- per-row softmax stats (m, s), computed ONCE ---------------
// one wave per row, bit-exact replica of the original butterfly. Also zeroes
// hist + counter (grid covers HSIZE threads). ms[r] = (max, denom).
__global__ __launch_bounds__(256) void k_softmax(
    const float* __restrict__ logits, float2* __restrict__ ms,
    int* __restrict__ hist, int* __restrict__ counter)
{
    int gid = blockIdx.x * 256 + threadIdx.x;
    if (gid < HSIZE) hist[gid] = 0;
    if (gid == 0) *counter = 0;

    int n = blockIdx.x * 4 + (threadIdx.x >> 6);
    int t = threadIdx.x & 63;

    float v1 = logits[n * C + t];
    float v2 = (t < C - 64) ? logits[n * C + 64 + t] : -INFINITY;
    float m = fmaxf(v1, v2);
    for (int off = 32; off; off >>= 1) m = fmaxf(m, __shfl_xor(m, off));
    float e1 = expf(v1 - m);
    float e2 = (t < C - 64) ? expf(v2 - m) : 0.0f;
    float s = e1 + e2;
    for (int off = 32; off; off >>= 1) s += __shfl_xor(s, off);

    if (t == 0) ms[n] = make_float2(m, s);
}

// ---------------- per-class: score -> threshold -> sort -> NMS --------------
// one block per foreground class. score = expf(logit - m)/s: identical bits
// to the old probsT entries (same m, s, expf, div). Only post-threshold
// candidates get decoded. Kept keys emitted into dense ckey[] via global
// atomic counter + score histogram. cbox/corig indexed by RANK (c*N + rank).
__global__ __launch_bounds__(256) void k_class(
    const float* __restrict__ logits, const float* __restrict__ boxreg,
    const float* __restrict__ pboxes, const float2* __restrict__ ms,
    u64* __restrict__ ckey, float4* __restrict__ cbox, int* __restrict__ corig,
    int* __restrict__ hist, int* __restrict__ counter)
{
    int c = blockIdx.x;            // foreground class (label = c+1)
    int cl = c + 1;
    int t = threadIdx.x;
    __shared__ u64    skey64[N];
    __shared__ int    scnt[256];
    __shared__ float4 sbox[N];
    __shared__ float  sarea[N];
    __shared__ int    skeep[N];

    float2 p0 = ms[t],       p1 = ms[t + 256];
    float2 p2 = ms[t + 512], p3 = ms[t + 768];
    float s0 = expf(logits[(t      ) * C + cl] - p0.x) / p0.y;
    float s1 = expf(logits[(t + 256) * C + cl] - p1.x) / p1.y;
    float s2 = expf(logits[(t + 512) * C + cl] - p2.x) / p2.y;
    float s3 = expf(logits[(t + 768) * C + cl] - p3.x) / p3.y;
    int f0 = s0 > SCORE_THRESH, f1 = s1 > SCORE_THRESH;
    int f2 = s2 > SCORE_THRESH, f3 = s3 > SCORE_THRESH;
    int mycount = f0 + f1 + f2 + f3;
    scnt[t] = mycount;
    __syncthreads();
    for (int off = 1; off < 256; off <<= 1) {
        int v = scnt[t];
        int a = (t >= off) ? scnt[t - off] : 0;
        __syncthreads();
        scnt[t] = v + a;
        __syncthreads();
    }
    int base = scnt[t] - mycount;
    int V = scnt[255];
    {
        int pos = base;
        if (f0) skey64[pos++] = ((u64)__float_as_uint(s0) << 32) | (u32)~(u32)(t);
        if (f1) skey64[pos++] = ((u64)__float_as_uint(s1) << 32) | (u32)~(u32)(t + 256);
        if (f2) skey64[pos++] = ((u64)__float_as_uint(s2) << 32) | (u32)~(u32)(t + 512);
        if (f3) skey64[pos++] = ((u64)__float_as_uint(s3) << 32) | (u32)~(u32)(t + 768);
    }
    __syncthreads();
    if (V == 0) return;

    if (V <= 64) {
        if (t < 64) {
            int lane = t;
            u64 key = (lane < V) ? skey64[lane] : 0ull;
            // descending bitonic over 64 lanes (keys unique; 0-pad sinks)
            for (int k = 2; k <= 64; k <<= 1) {
                for (int j = k >> 1; j > 0; j >>= 1) {
                    u64 other = __shfl_xor(key, j);
                    bool takeMax = (((lane & j) == 0) == ((lane & k) == 0));
                    bool gt = key > other;
                    key = (takeMax == gt) ? key : other;
                }
            }
            bool act = key != 0ull;
            float4 b = make_float4(0.f, 0.f, 0.f, 0.f);
            float area = 0.0f;
            if (act) {
                int idx = (int)(~(u32)(key & 0xffffffffu));
                b = decode_box(pboxes, boxreg, idx, cl);
                area = (b.z - b.x + 1.0f) * (b.w - b.y + 1.0f);
                cbox[c * N + lane]  = b;
                corig[c * N + lane] = idx;
            }
            int kept = act ? 1 : 0;
            for (int i = 0; i + 1 < V; ++i) {
                int   ki  = __shfl(kept, i);
                float bix = __shfl(b.x, i), biy = __shfl(b.y, i);
                float biz = __shfl(b.z, i), biw = __shfl(b.w, i);
                float ai  = __shfl(area, i);
                if (ki && lane > i && kept) {
                    float lx = fmaxf(bix, b.x), ly = fmaxf(biy, b.y);
                    float rx = fminf(biz, b.z), ry = fminf(biw, b.w);
                    float ww = fmaxf(rx - lx + 1.0f, 0.0f);
                    float hh = fmaxf(ry - ly + 1.0f, 0.0f);
                    float inter = ww * hh;
                    float iou = inter / (ai + area - inter);
                    if (iou > NMS_THRESH) kept = 0;
                }
            }
            if (kept) {
                int pos = atomicAdd(counter, 1);
                u32 sb = (u32)(key >> 32);
                ckey[pos] = ((u64)sb << 32) | (u64)(u32)~(u32)(c * N + lane);
                atomicAdd(&hist[(int)(sb >> 16) - HBASE], 1);
            }
        }
        return;
    }

    // ---------- fallback: V > 64, LDS bitonic on P = next pow2 ----------
    int P = 128;
    while (P < V) P <<= 1;
    for (int i = V + t; i < P; i += 256) skey64[i] = 0ull;
    __syncthreads();
    for (int k = 2; k <= P; k <<= 1) {
        for (int j = k >> 1; j > 0; j >>= 1) {
            for (int i = t; i < P; i += 256) {
                int ixj = i ^ j;
                if (ixj > i) {
                    u64 a = skey64[i], bb = skey64[ixj];
                    bool desc = ((i & k) == 0);
                    if (desc ? (a < bb) : (a > bb)) { skey64[i] = bb; skey64[ixj] = a; }
                }
            }
            __syncthreads();
        }
    }
    for (int p = t; p < V; p += 256) {
        int idx = (int)(~(u32)(skey64[p] & 0xffffffffu));
        float4 b = decode_box(pboxes, boxreg, idx, cl);
        sbox[p]  = b;
        sarea[p] = (b.z - b.x + 1.0f) * (b.w - b.y + 1.0f);
        skeep[p] = 1;
        cbox[c * N + p]  = b;
        corig[c * N + p] = idx;
    }
    __syncthreads();
    for (int i = 0; i < V; ++i) {
        if (skeep[i]) {
            float4 bi = sbox[i];
            float  ai = sarea[i];
            for (int j = i + 1 + t; j < V; j += 256) {
                if (skeep[j]) {
                    float4 bj = sbox[j];
                    float lx = fmaxf(bi.x, bj.x), ly = fmaxf(bi.y, bj.y);
                    float rx = fminf(bi.z, bj.z), ry = fminf(bi.w, bj.w);
                    float ww = fmaxf(rx - lx + 1.0f, 0.0f);
                    float hh = fmaxf(ry - ly + 1.0f, 0.0f);
                    float inter = ww * hh;
                    float iou = inter / (ai + sarea[j] - inter);
                    if (iou > NMS_THRESH) skeep[j] = 0;
                }
            }
        }
        __syncthreads();
    }
    for (int p = t; p < V; p += 256) {
        if (skeep[p]) {
            int pos = atomicAdd(counter, 1);
            u32 sb = (u32)(skey64[p] >> 32);
            ckey[pos] = ((u64)sb << 32) | (u64)(u32)~(u32)(c * N + p);
            atomicAdd(&hist[(int)(sb >> 16) - HBASE], 1);
        }
    }
}

// ---------------- exact top-K via radix-select + small bitonic sort --------
__global__ __launch_bounds__(1024) void k_select(
    const int* __restrict__ counter, u64* ckey, const int* __restrict__ hist,
    float* __restrict__ sel_score, int* __restrict__ sel_flat)
{
    int t = threadIdx.x;
    __shared__ u64 keys[SELCAP];
    __shared__ int partial[1024];
    __shared__ int sb_bstar, scount;
    __shared__ u64 wk[16];
    __shared__ int wp[16];

    int M = *counter;
    if (t == 0) { sb_bstar = 0; scount = 0; }

    // phase 1: suffix scan of 1024-bucket histogram -> bucket of K-th key
    int lsum = hist[t];
    partial[t] = lsum;
    __syncthreads();
    for (int off = 1; off < 1024; off <<= 1) {
        int v = partial[t];
        int a = (t + off < 1024) ? partial[t + off] : 0;
        __syncthreads();
        partial[t] = v + a;
        __syncthreads();
    }
    int base = partial[t] - lsum;              // keys in buckets above t
    if (base < K && base + lsum >= K) sb_bstar = t;
    __syncthreads();
    int bstar = sb_bstar;

    // phase 2: compact keys with bucket >= bstar
    for (int p = t; p < M; p += 1024) {
        u64 kk = ckey[p];
        int b = (int)((kk >> 48) & 0xFFFF) - HBASE;
        if (b >= bstar) {
            int pos = atomicAdd(&scount, 1);
            if (pos < SELCAP) keys[pos] = kk;
        }
    }
    __syncthreads();
    int cnt = scount;

    if (cnt > SELCAP) {
        // exact fallback (tie flood): K rounds of argmax over dense ckey
        for (int k = 0; k < K; ++k) {
            u64 key = 0ull; int pos = -1;
            for (int p = t; p < M; p += 1024) {
                u64 kk = ckey[p];
                if (kk > key) { key = kk; pos = p; }
            }
            for (int off = 32; off; off >>= 1) {
                u64 ok2 = __shfl_down(key, off);
                int op = __shfl_down(pos, off);
                if (ok2 > key) { key = ok2; pos = op; }
            }
            if ((t & 63) == 0) { wk[t >> 6] = key; wp[t >> 6] = pos; }
            __syncthreads();
            if (t == 0) {
                for (int w = 1; w < 16; ++w)
                    if (wk[w] > key) { key = wk[w]; pos = wp[w]; }
                if (key != 0ull) {
                    sel_score[k] = __uint_as_float((u32)(key >> 32));
                    sel_flat[k]  = (int)(~(u32)(key & 0xffffffffu));
                    ckey[pos] = 0ull;
                } else { sel_score[k] = 0.0f; sel_flat[k] = 0; }
            }
            __syncthreads();
        }
        return;
    }

    // phase 3: bitonic sort padded selection, emit top K
    int P = 128;
    while (P < cnt) P <<= 1;
    for (int i = cnt + t; i < P; i += 1024) keys[i] = 0ull;
    __syncthreads();
    for (int k = 2; k <= P; k <<= 1) {
        for (int j = k >> 1; j > 0; j >>= 1) {
            for (int i = t; i < P; i += 1024) {
                int ixj = i ^ j;
                if (ixj > i) {
                    u64 a = keys[i], b = keys[ixj];
                    bool desc = ((i & k) == 0);
                    if (desc ? (a < b) : (a > b)) { keys[i] = b; keys[ixj] = a; }
                }
            }
            __syncthreads();
        }
    }
    if (t < K) {
        u64 key = keys[t];
        sel_score[t] = __uint_as_float((u32)(key >> 32));
        sel_flat[t]  = (int)(~(u32)(key & 0xffffffffu));
    }
}

// ---------------- gather outputs ------------------------------------------
// out layout: boxes[K*4] | scores[K] | feats[K*F] | labels[K]  (all f32)
__global__ __launch_bounds__(256) void k_gather(
    const float* __restrict__ sel_score, const int* __restrict__ sel_flat,
    const int* __restrict__ corig, const float4* __restrict__ cbox,
    const float* __restrict__ feats, float* __restrict__ out)
{
    int k = blockIdx.x, t = threadIdx.x;
    float s = sel_score[k];
    bool ok = s > 0.0f;
    float4 b = make_float4(0.f, 0.f, 0.f, 0.f);
    int label = 0, orig = 0;
    if (ok) {
        int flat = sel_flat[k];        // c*N + rank
        orig  = corig[flat];
        b     = cbox[flat];
        label = (flat >> 10) + 1;      // N = 1024
    }
    if (t == 0) {
        out[k * 4 + 0] = b.x; out[k * 4 + 1] = b.y;
        out[k * 4 + 2] = b.z; out[k * 4 + 3] = b.w;
        out[K * 4 + k] = ok ? s : 0.0f;
        out[K * 4 + K + K * F + k] = (float)label;
    }
    const float4* src = (const float4*)(feats + (size_t)orig * F);
    float4* dst = (float4*)(out + K * 4 + K + (size_t)k * F);
    float4 z = make_float4(0.f, 0.f, 0.f, 0.f);
    if (t < F / 4) dst[t] = ok ? src[t] : z;
}

// ---------------------------------------------------------------------------
extern "C" void kernel_launch(void* const* d_in, const int* in_sizes, int n_in,
                              void* d_out, int out_size, void* d_ws, size_t ws_size,
                              hipStream_t stream)
{
    const float* logits = (const float*)d_in[0];   // [N,C]
    const float* boxreg = (const float*)d_in[1];   // [N,C*4]
    const float* pboxes = (const float*)d_in[2];   // [N,4]
    const float* feats  = (const float*)d_in[3];   // [N,F]
    float* out = (float*)d_out;

    char* ws = (char*)d_ws;
    size_t off = 0;
    auto alloc = [&](size_t bytes) {
        size_t cur = off;
        off = (off + bytes + 255) & ~(size_t)255;
        return cur;
    };
    u64*    ckey      = (u64*)   (ws + alloc(sizeof(u64)    * MAXC));
    float4* cbox      = (float4*)(ws + alloc(sizeof(float4) * NC1 * N));
    int*    corig     = (int*)   (ws + alloc(sizeof(int)    * NC1 * N));
    float2* ms        = (float2*)(ws + alloc(sizeof(float2) * N));
    int*    hist      = (int*)   (ws + alloc(sizeof(int)    * HSIZE));
    int*    counter   = (int*)   (ws + alloc(sizeof(int)));
    float*  sel_score = (float*) (ws + alloc(sizeof(float)  * K));
    int*    sel_flat  = (int*)   (ws + alloc(sizeof(int)    * K));

    hipLaunchKernelGGL(k_softmax, dim3(N / 4), dim3(256), 0, stream,
                       logits, ms, hist, counter);
    hipLaunchKernelGGL(k_class, dim3(NC1), dim3(256), 0, stream,
                       logits, boxreg, pboxes, ms, ckey, cbox, corig, hist, counter);
    hipLaunchKernelGGL(k_select, dim3(1), dim3(1024), 0, stream,
                       counter, ckey, hist, sel_score, sel_flat);
    hipLaunchKernelGGL(k_gather, dim3(K), dim3(256), 0, stream,
                       sel_score, sel_flat, corig, cbox, feats, out);
}